// Round 6
// baseline (604.472 us; speedup 1.0000x reference)
//
#include <hip/hip_runtime.h>
#include <math.h>

// Problem constants (B=2, H=W=256, DIM=INNER=64, WS=8, OWS=12, HEADS=4, DH=16)
#define NPIX   65536      // 256*256
#define NPIXT  131072     // B * NPIX
#define NW     1024       // 32*32 windows per batch
#define KEEP   512

// Layouts: x, condition_global, h1, sa, out = NCHW (as given / required).
// qs, ks, vs, amix = NHWC: t[(b*NPIX + p)*64 + c]  (64 contiguous ch/pixel).
// xm = window-major: xm[(b<<16) + win*64 + (h&7)*8 + (w&7)].

// readlane broadcast helper: value from lane `l` of `v` (compile-time l ->
// immediate lane select).  Result is wave-uniform (SGPR), consumed as the
// scalar operand of v_fmac -> zero LDS traffic for shared data.
__device__ __forceinline__ float bcast(float v, int l) {
    return __int_as_float(__builtin_amdgcn_readlane(__float_as_int(v), l));
}

// ---------------------------------------------------------------------------
// K1: fused q/k/v 1x1 convs.  (round-5 version, unchanged: lane-distributed
// weights + readlane broadcast, no LDS, 2 px/lane.)
// ---------------------------------------------------------------------------
__global__ __launch_bounds__(256) void k_qkv(
    const float* __restrict__ x,
    const float* __restrict__ Wq, const float* __restrict__ bq,
    const float* __restrict__ Wk, const float* __restrict__ bk,
    const float* __restrict__ Wv, const float* __restrict__ bv,
    float* __restrict__ qs, float* __restrict__ ks, float* __restrict__ vs)
{
    const int tid  = threadIdx.x;
    const int lane = tid & 63;
    const int og   = __builtin_amdgcn_readfirstlane(tid >> 6);  // wave-uniform
    const int tile = blockIdx.x;                 // 0..1023
    const int b    = tile >> 9;
    const int p0   = (tile & 511) << 7;          // 128-px tile
    const int p    = p0 + 2 * lane;
    const int gp   = (b << 16) + p;
    const int wo   = og * 16;

    const float* Ws[3]   = {Wq, Wk, Wv};
    const float* bias[3] = {bq, bk, bv};
    float* outs[3] = {qs + (size_t)gp * 64, ks + (size_t)gp * 64, vs + (size_t)gp * 64};
    const float* xg = x + ((size_t)b * 64) * NPIX + p;

    #pragma unroll
    for (int m = 0; m < 3; ++m) {
        const float* Wm = Ws[m];
        float w[16];
        #pragma unroll
        for (int j = 0; j < 16; ++j) w[j] = Wm[(wo + j) * 64 + lane];

        float acc0[16], acc1[16];
        #pragma unroll
        for (int j = 0; j < 16; ++j) { acc0[j] = 0.f; acc1[j] = 0.f; }

        #pragma unroll 8
        for (int c = 0; c < 64; ++c) {           // ascending -> bit-identical
            const float2 xv = *(const float2*)(xg + (size_t)c * NPIX);
            #pragma unroll
            for (int j = 0; j < 16; ++j) {
                const float wv = bcast(w[j], c); // SGPR weight
                acc0[j] += wv * xv.x;
                acc1[j] += wv * xv.y;
            }
        }

        const float* bb = bias[m];
        float* o0 = outs[m];
        #pragma unroll
        for (int j4 = 0; j4 < 4; ++j4) {
            float4 v0, v1;
            v0.x = acc0[j4*4+0] + bb[wo + j4*4+0]; v1.x = acc1[j4*4+0] + bb[wo + j4*4+0];
            v0.y = acc0[j4*4+1] + bb[wo + j4*4+1]; v1.y = acc1[j4*4+1] + bb[wo + j4*4+1];
            v0.z = acc0[j4*4+2] + bb[wo + j4*4+2]; v1.z = acc1[j4*4+2] + bb[wo + j4*4+2];
            v0.w = acc0[j4*4+3] + bb[wo + j4*4+3]; v1.w = acc1[j4*4+3] + bb[wo + j4*4+3];
            *(float4*)(o0 + wo + j4*4)      = v0;
            *(float4*)(o0 + 64 + wo + j4*4) = v1;
        }
    }
}

// ---------------------------------------------------------------------------
// K2: conditioning conv (68 -> 17) + channel LayerNorm + lrelu; emits xm.
// ROUND-6: pinW (1156 floats) was read per-pixel as uniform-address loads
// (broadcast waste, same pathology as round-4 weights).  Now lane-
// distributed into 19 regs + compile-time readlane broadcast.  Values and
// accumulation order are IDENTICAL (same floats, same += sequence:
// c 0..63 ascending per oc, then the chained c64..67 term with the same
// grouping) -> bit-identical h1/xm -> identical partition.
// ---------------------------------------------------------------------------
__global__ __launch_bounds__(256) void k_cond(
    const float* __restrict__ vs, const float* __restrict__ cg,
    const float* __restrict__ pinW, const float* __restrict__ pinb,
    const float* __restrict__ lnw, const float* __restrict__ lnb,
    float* __restrict__ h1, float* __restrict__ xm)
{
    const int tid  = threadIdx.x;
    const int lane = tid & 63;
    const int gp = blockIdx.x * 256 + tid;
    const int b  = gp >> 16;
    const int p  = gp & 65535;
    const int h  = p >> 8;
    const int w  = p & 255;

    // lane-distributed pinW: pw[k] holds pinW[k*64 + lane]
    float pw[19];
    #pragma unroll
    for (int k = 0; k < 19; ++k) {
        const int idx = k * 64 + lane;
        pw[k] = (idx < 1156) ? pinW[idx] : 0.f;
    }

    float acc[17];
    #pragma unroll
    for (int oc = 0; oc < 17; ++oc) acc[oc] = pinb[oc];

    const float* vp = vs + (size_t)gp * 64;
    #pragma unroll 4
    for (int c4 = 0; c4 < 16; ++c4) {
        const float4 v4 = *(const float4*)(vp + c4 * 4);
        const float vv[4] = {v4.x, v4.y, v4.z, v4.w};
        #pragma unroll
        for (int k = 0; k < 4; ++k) {
            const int c = c4 * 4 + k;            // ascending 0..63
            #pragma unroll
            for (int oc = 0; oc < 17; ++oc) {
                const int idx = oc * 68 + c;     // compile-time
                acc[oc] += bcast(pw[idx >> 6], idx & 63) * vv[k];
            }
        }
    }
    const float c64 = cg[(b * 2 + 0) * NPIX + p];
    const float c65 = cg[(b * 2 + 1) * NPIX + p];
    const float c66 = -1.f + 2.f * (float)(h & 7) / 7.f;
    const float c67 = -1.f + 2.f * (float)(w & 7) / 7.f;
    #pragma unroll
    for (int oc = 0; oc < 17; ++oc) {
        const int i64 = oc * 68 + 64, i65 = oc * 68 + 65;
        const int i66 = oc * 68 + 66, i67 = oc * 68 + 67;
        acc[oc] += bcast(pw[i64 >> 6], i64 & 63) * c64 +
                   bcast(pw[i65 >> 6], i65 & 63) * c65 +
                   bcast(pw[i66 >> 6], i66 & 63) * c66 +
                   bcast(pw[i67 >> 6], i67 & 63) * c67;
    }

    float u = 0.f;
    #pragma unroll
    for (int oc = 0; oc < 17; ++oc) u += acc[oc];
    u *= (1.f / 17.f);
    float s = 0.f;
    #pragma unroll
    for (int oc = 0; oc < 17; ++oc) { const float d = acc[oc] - u; s += d * d; }
    s *= (1.f / 17.f);
    const float rstd = rsqrtf(s + 1e-6f);

    float xsum = 0.f;
    #pragma unroll
    for (int oc = 0; oc < 17; ++oc) {
        float hv = lnw[oc] * (acc[oc] - u) * rstd + lnb[oc];
        hv = (hv >= 0.f) ? hv : 0.1f * hv;
        h1[(b * 17 + oc) * NPIX + p] = hv;
        xsum += hv;
    }
    const int win = (h >> 3) * 32 + (w >> 3);
    const int idx = ((h & 7) << 3) | (w & 7);
    xm[(b << 16) + win * 64 + idx] = xsum * (1.f / 17.f);
}

// ---------------------------------------------------------------------------
// K3: 3x3 conv (17 -> 1) + sigmoid -> sa.  (unchanged)
// ---------------------------------------------------------------------------
__global__ __launch_bounds__(256) void k_sa(
    const float* __restrict__ h1, const float* __restrict__ saW,
    const float* __restrict__ sab, float* __restrict__ sa)
{
    __shared__ float S[17 * 3 * 256];
    const int tid = threadIdx.x;
    const int b   = blockIdx.x >> 8;
    const int row = blockIdx.x & 255;

    for (int i = tid; i < 3264; i += 256) {
        const int ch  = i / 192;
        const int rem = i - ch * 192;
        const int dr  = rem >> 6;
        const int c4  = rem & 63;
        const int rr  = row + dr - 1;
        float4 v = {0.f, 0.f, 0.f, 0.f};
        if ((unsigned)rr < 256u)
            v = *(const float4*)(h1 + ((size_t)(b * 17 + ch)) * NPIX + rr * 256 + c4 * 4);
        *(float4*)&S[(ch * 3 + dr) * 256 + c4 * 4] = v;
    }
    __syncthreads();

    const int w = tid;
    float acc = sab[0];
    #pragma unroll 1
    for (int ch = 0; ch < 17; ++ch) {
        #pragma unroll
        for (int dr = 0; dr < 3; ++dr) {
            const float* Sp = &S[(ch * 3 + dr) * 256];
            const float m  = Sp[w];
            const float l  = (w > 0)   ? Sp[w - 1] : 0.f;
            const float r_ = (w < 255) ? Sp[w + 1] : 0.f;
            const float* Wp = saW + (ch * 3 + dr) * 3;
            acc += Wp[0] * l + Wp[1] * m + Wp[2] * r_;
        }
    }
    sa[b * NPIX + row * 256 + w] = 1.f / (1.f + __expf(-acc));
}

// ---------------------------------------------------------------------------
// K4: window scoring MLP + stable-argsort partition.  (unchanged)
// ---------------------------------------------------------------------------
__global__ __launch_bounds__(1024) void k_score_select(
    const float* __restrict__ xm,
    const float* __restrict__ m1W, const float* __restrict__ m1b,
    const float* __restrict__ m2W, const float* __restrict__ m2b,
    int* __restrict__ flag, int* __restrict__ kept)
{
    __shared__ float sc[NW];
    const int b = blockIdx.x;
    const int t = threadIdx.x;

    float z[8];
    #pragma unroll
    for (int jj = 0; jj < 8; ++jj) z[jj] = m1b[jj];

    const float* xw = xm + (b << 16) + t * 64;
    #pragma unroll 4
    for (int t4 = 0; t4 < 16; ++t4) {
        const float4 v4 = *(const float4*)(xw + t4 * 4);
        const float vv[4] = {v4.x, v4.y, v4.z, v4.w};
        #pragma unroll
        for (int k = 0; k < 4; ++k) {
            const int tt = t4 * 4 + k;           // ascending 0..63
            #pragma unroll
            for (int jj = 0; jj < 8; ++jj)
                z[jj] += m1W[jj * 64 + tt] * vv[k];
        }
    }
    #pragma unroll
    for (int jj = 0; jj < 8; ++jj) z[jj] = (z[jj] >= 0.f) ? z[jj] : 0.1f * z[jj];

    float l0 = m2b[0], l1 = m2b[1];
    #pragma unroll
    for (int jj = 0; jj < 8; ++jj) { l0 += m2W[jj] * z[jj]; l1 += m2W[8 + jj] * z[jj]; }
    const float mx = fmaxf(l0, l1);
    const float e0 = expf(l0 - mx), e1 = expf(l1 - mx);
    sc[t] = e0 / (e0 + e1);
    __syncthreads();

    const float s = sc[t];
    int cnt = 0;
    for (int jq = 0; jq < NW; jq += 4) {
        const float4 s4 = *(const float4*)&sc[jq];
        cnt += (s4.x > s) || (s4.x == s && (jq + 0) < t);
        cnt += (s4.y > s) || (s4.y == s && (jq + 1) < t);
        cnt += (s4.z > s) || (s4.z == s && (jq + 2) < t);
        cnt += (s4.w > s) || (s4.w == s && (jq + 3) < t);
    }
    flag[b * NW + t] = (cnt < KEEP) ? 1 : 0;
    if (cnt < KEEP) kept[b * KEEP + cnt] = t;
}

// ---------------------------------------------------------------------------
// K5: windowed attention, HYBRID core (round-6).
// Measured endpoints: all-LDS broadcast = 91us (LDS-pipe-bound: 1152
// uniform b128/wave x ~12cyc x 16 waves/CU ~= 92us); all-readlane = 134us
// (VALU-bound: readlane ~2x a VALU op effective, VALUBusy 74%).
// Hybrid: K via LDS uniform b128 (4 reads -> 16 fma, cheap on VALU); V via
// lane-distributed global + readlane (halves LDS traffic; adds 16 readlane
// + 16 fma per key, still under the halved LDS time).  K staged ONCE for
// all 144 keys (36.9KB, one barrier pair, 4 blocks/CU).
// Per-key FP sequence identical to rounds 3-5: key order ascending
// (r*12 + 4*gi + kk), s = srow + cw then ascending-d dot, sum += e,
// ascending-d PV -> bit-identical amix.
// ---------------------------------------------------------------------------
__global__ __launch_bounds__(256, 4) void k_attn(
    const float* __restrict__ qs, const float* __restrict__ ks,
    const float* __restrict__ vs, const int* __restrict__ kept,
    const float* __restrict__ relh, const float* __restrict__ relw,
    float* __restrict__ amix)
{
    __shared__ float SK[144 * 64];   // 36864 B: K for all 144 patch px
    const int b    = blockIdx.y;
    const int win  = kept[b * KEEP + blockIdx.x];
    const int wy = win >> 5, wx = win & 31;
    const int tid  = threadIdx.x;
    const int head = __builtin_amdgcn_readfirstlane(tid >> 6);
    const int lane = tid & 63;
    const int choff = head * 16;
    const size_t bbase = (size_t)b * NPIX;
    const int px0 = (wy * 8) * 256 + wx * 8;
    const int qrow = lane >> 3, qcol = lane & 7;
    const int sub = lane >> 4, d_ = lane & 15;
    const int wy8 = wy * 8 - 2, wx8 = wx * 8 - 2;

    // ---- stage K for all 144 keys (2304 float4, 9/thread, coalesced) ----
    #pragma unroll
    for (int it = 0; it < 9; ++it) {
        const int i   = it * 256 + tid;
        const int pxl = i >> 4;                  // 0..143
        const int c4  = i & 15;
        const int rl  = pxl / 12;
        const int col = pxl - rl * 12;
        const int ry  = wy8 + rl;
        const int cx  = wx8 + col;
        float4 kv = {0.f, 0.f, 0.f, 0.f};
        if ((unsigned)ry < 256u && (unsigned)cx < 256u)
            kv = *(const float4*)(ks + (bbase + (size_t)(ry * 256 + cx)) * 64 + c4 * 4);
        *(float4*)&SK[pxl * 64 + c4 * 4] = kv;
    }

    // ---- q direct from global (same values, x0.25) ----
    float q[16];
    {
        const float* qp = qs + (bbase + px0 + qrow * 256 + qcol) * 64 + choff;
        #pragma unroll
        for (int j4 = 0; j4 < 4; ++j4) {
            const float4 v = *(const float4*)(qp + j4 * 4);
            q[j4 * 4 + 0] = v.x * 0.25f; q[j4 * 4 + 1] = v.y * 0.25f;
            q[j4 * 4 + 2] = v.z * 0.25f; q[j4 * 4 + 3] = v.w * 0.25f;
        }
    }

    // ---- column rel-pos coefficients (identical arithmetic) ----
    float cw[12];
    #pragma unroll
    for (int k = 0; k < 12; ++k) {
        const float* rw = relw + (k - qcol + 11) * 16;
        float sw = 0.f;
        #pragma unroll
        for (int j4 = 0; j4 < 4; ++j4) {
            const float4 w4 = *(const float4*)(rw + j4 * 4);
            sw += q[j4*4+0]*w4.x + q[j4*4+1]*w4.y + q[j4*4+2]*w4.z + q[j4*4+3]*w4.w;
        }
        cw[k] = sw;
    }

    const int laneoff = choff + d_;

    float sum = 0.f;
    float vo[16];
    #pragma unroll
    for (int d = 0; d < 16; ++d) vo[d] = 0.f;

    __syncthreads();   // K staged

    #pragma unroll 1
    for (int r = 0; r < 12; ++r) {               // patch row (12 keys each)
        const int ry = wy8 + r;
        const bool rowok = (unsigned)ry < 256u;

        // row rel-pos coefficient (same instruction sequence)
        const float* rh = relh + (r - qrow + 11) * 16;
        float srow = 0.f;
        #pragma unroll
        for (int j4 = 0; j4 < 4; ++j4) {
            const float4 h4 = *(const float4*)(rh + j4 * 4);
            srow += q[j4*4+0]*h4.x + q[j4*4+1]*h4.y + q[j4*4+2]*h4.z + q[j4*4+3]*h4.w;
        }

        #pragma unroll
        for (int gi = 0; gi < 3; ++gi) {         // 4-key groups within the row
            // V for this group, lane-distributed from global
            const int cx = wx8 + 4 * gi + sub;
            float vg = 0.f;
            if (rowok && (unsigned)cx < 256u)
                vg = vs[(bbase + (size_t)(ry * 256 + cx)) * 64 + laneoff];

            #pragma unroll
            for (int kk = 0; kk < 4; ++kk) {     // key col = 4*gi + kk
                const float* kb = &SK[(r * 12 + 4 * gi + kk) * 64 + choff]; // uniform
                const float4 k0 = *(const float4*)(kb + 0);
                const float4 k1 = *(const float4*)(kb + 4);
                const float4 k2 = *(const float4*)(kb + 8);
                const float4 k3 = *(const float4*)(kb + 12);
                float s = srow + cw[4 * gi + kk];
                s += k0.x*q[0];  s += k0.y*q[1];  s += k0.z*q[2];  s += k0.w*q[3];
                s += k1.x*q[4];  s += k1.y*q[5];  s += k1.z*q[6];  s += k1.w*q[7];
                s += k2.x*q[8];  s += k2.y*q[9];  s += k2.z*q[10]; s += k2.w*q[11];
                s += k3.x*q[12]; s += k3.y*q[13]; s += k3.z*q[14]; s += k3.w*q[15];
                const float e = __expf(s);
                sum += e;
                // V broadcast in two 8-batches (bounds live registers);
                // each vo[d] chain gets the same += e*V term -> bit-identical
                float vd[8];
                #pragma unroll
                for (int d = 0; d < 8; ++d) vd[d] = bcast(vg, kk * 16 + d);
                #pragma unroll
                for (int d = 0; d < 8; ++d) vo[d] += e * vd[d];
                #pragma unroll
                for (int d = 0; d < 8; ++d) vd[d] = bcast(vg, kk * 16 + 8 + d);
                #pragma unroll
                for (int d = 0; d < 8; ++d) vo[8 + d] += e * vd[d];
            }
        }
    }

    // ---- epilogue: normalize, direct store of this head's 16-ch slice ----
    const float inv = 1.f / sum;
    float* op = amix + (bbase + px0 + qrow * 256 + qcol) * 64 + choff;
    #pragma unroll
    for (int j4 = 0; j4 < 4; ++j4) {
        float4 v;
        v.x = vo[j4*4+0] * inv; v.y = vo[j4*4+1] * inv;
        v.z = vo[j4*4+2] * inv; v.w = vo[j4*4+3] * inv;
        *(float4*)(op + j4 * 4) = v;
    }
}

// ---------------------------------------------------------------------------
// K6: final 1x1 conv (64 -> 64) with fused easy path.  (round-5 version,
// unchanged: lane-distributed weights + readlane; x staged in LDS.)
// ---------------------------------------------------------------------------
__global__ __launch_bounds__(256) void k_out_f(
    const float* __restrict__ amix, const float* __restrict__ vs,
    const float* __restrict__ sa, const int* __restrict__ flag,
    const float* __restrict__ W, const float* __restrict__ bias,
    float* __restrict__ out)
{
    __shared__ float xs[64][130];                // 33.3 KB
    __shared__ float smult[128];
    __shared__ int   sflag[128];
    const int tid  = threadIdx.x;
    const int lane = tid & 63;
    const int og   = __builtin_amdgcn_readfirstlane(tid >> 6);
    const int tile = blockIdx.x;                 // 0..1023
    const int b    = tile >> 9;
    const int p0   = (tile & 511) << 7;          // 128-px tile
    const int wo   = og * 16;

    if (tid < 128) {
        const int p   = p0 + tid;
        const int h   = p >> 8, w_ = p & 255;
        const int win = (h >> 3) * 32 + (w_ >> 3);
        const int fl  = flag[b * NW + win];
        sflag[tid] = fl;
        smult[tid] = fl ? 1.f : sa[(b << 16) + p];
    }
    __syncthreads();

    #pragma unroll
    for (int it = 0; it < 8; ++it) {
        const int i   = it * 256 + tid;
        const int pxl = i >> 4;                  // 0..127
        const int c4  = i & 15;
        const int gpl = (b << 16) + p0 + pxl;
        const float* src = (sflag[pxl] ? amix : vs) + (size_t)gpl * 64;
        const float m = smult[pxl];
        const float4 v = *(const float4*)(src + c4 * 4);
        xs[c4 * 4 + 0][pxl] = v.x * m;
        xs[c4 * 4 + 1][pxl] = v.y * m;
        xs[c4 * 4 + 2][pxl] = v.z * m;
        xs[c4 * 4 + 3][pxl] = v.w * m;
    }
    __syncthreads();

    float w[16];
    #pragma unroll
    for (int j = 0; j < 16; ++j) w[j] = W[(wo + j) * 64 + lane];

    float acc0[16], acc1[16];
    #pragma unroll
    for (int j = 0; j < 16; ++j) { acc0[j] = 0.f; acc1[j] = 0.f; }

    #pragma unroll 8
    for (int c = 0; c < 64; ++c) {               // ascending -> bit-identical
        const float2 xv = *(const float2*)&xs[c][2 * lane];
        #pragma unroll
        for (int j = 0; j < 16; ++j) {
            const float wv = bcast(w[j], c);
            acc0[j] += wv * xv.x;
            acc1[j] += wv * xv.y;
        }
    }

    const int p    = p0 + 2 * lane;
    const int base = (b << 6) * NPIX + p;
    #pragma unroll
    for (int j = 0; j < 16; ++j) {
        const float bj = bias[wo + j];
        out[base +     (wo + j) * NPIX] = acc0[j] + bj;
        out[base + 1 + (wo + j) * NPIX] = acc1[j] + bj;
    }
}

// ---------------------------------------------------------------------------
extern "C" void kernel_launch(void* const* d_in, const int* in_sizes, int n_in,
                              void* d_out, int out_size, void* d_ws, size_t ws_size,
                              hipStream_t stream)
{
    const float* x    = (const float*)d_in[0];
    const float* cg   = (const float*)d_in[1];
    const float* Wq   = (const float*)d_in[2];
    const float* bq   = (const float*)d_in[3];
    const float* Wk   = (const float*)d_in[4];
    const float* bk   = (const float*)d_in[5];
    const float* Wv   = (const float*)d_in[6];
    const float* bv   = (const float*)d_in[7];
    const float* Wout = (const float*)d_in[8];
    const float* bout = (const float*)d_in[9];
    const float* relh = (const float*)d_in[10];
    const float* relw = (const float*)d_in[11];
    const float* pinW = (const float*)d_in[12];
    const float* pinb = (const float*)d_in[13];
    const float* lnw  = (const float*)d_in[14];
    const float* lnb  = (const float*)d_in[15];
    const float* saW  = (const float*)d_in[16];
    const float* sab  = (const float*)d_in[17];
    const float* m1W  = (const float*)d_in[18];
    const float* m1b  = (const float*)d_in[19];
    const float* m2W  = (const float*)d_in[20];
    const float* m2b  = (const float*)d_in[21];
    float* out = (float*)d_out;

    // workspace layout (floats); qs doubles as the assembled "amix" tensor
    float* ws    = (float*)d_ws;
    float* qs    = ws;                       // 64*NPIXT (NHWC, aliased amix)
    float* ks    = qs + 8388608;             // NHWC
    float* vs    = ks + 8388608;             // NHWC
    float* h1    = vs + 8388608;             // 17 * NPIXT (NCHW)
    float* xm    = h1 + 17 * NPIXT;          // NPIXT (window-major)
    float* sa    = xm + NPIXT;               // NPIXT
    int*   flag  = (int*)(sa + NPIXT);       // 2048
    int*   kept  = flag + 2048;              // 1024

    k_qkv         <<<1024, 256, 0, stream>>>(x, Wq, bq, Wk, bk, Wv, bv, qs, ks, vs);
    k_cond        <<<NPIXT / 256, 256, 0, stream>>>(vs, cg, pinW, pinb, lnw, lnb, h1, xm);
    k_sa          <<<512, 256, 0, stream>>>(h1, saW, sab, sa);
    k_score_select<<<2, 1024, 0, stream>>>(xm, m1W, m1b, m2W, m2b, flag, kept);
    k_attn        <<<dim3(KEEP, 2), 256, 0, stream>>>(qs, ks, vs, kept, relh, relw, qs);
    k_out_f       <<<1024, 256, 0, stream>>>(qs, vs, sa, flag, Wout, bout, out);
}

// Round 7
// 359.535 us; speedup vs baseline: 1.6813x; 1.6813x over previous
//
#include <hip/hip_runtime.h>
#include <math.h>

// Problem constants (B=2, H=W=256, DIM=INNER=64, WS=8, OWS=12, HEADS=4, DH=16)
#define NPIX   65536      // 256*256
#define NPIXT  131072     // B * NPIX
#define NW     1024       // 32*32 windows per batch
#define KEEP   512

// Layouts: x, condition_global, h1, sa, out = NCHW (as given / required).
// qs, ks, vs, amix = NHWC: t[(b*NPIX + p)*64 + c]  (64 contiguous ch/pixel).
// xm = window-major: xm[(b<<16) + win*64 + (h&7)*8 + (w&7)].

// readlane broadcast: wave-uniform SGPR result, consumed as the scalar
// operand of v_fmac.  ~4 cyc effective (measured r5) but on the VALU pipe,
// freeing the LDS pipe.
__device__ __forceinline__ float bcast(float v, int l) {
    return __int_as_float(__builtin_amdgcn_readlane(__float_as_int(v), l));
}

// ---------------------------------------------------------------------------
// K1: fused q/k/v 1x1 convs, og-split, Wt-in-LDS (r4 structure, 95us) with
// 2 px/lane: the uniform weight b128 reads are per-WAVE cost (shared by all
// lanes), so halving the wave count halves the LDS-pipe time (the r4
// bottleneck: 768 b128 x ~12cyc x 32 waves/CU ~= measured 95us).
// acc = 2x16 = 32 regs + temps ~= 60 live -> fits 64, no spill (r1 lesson).
// Per (px,og,j) accumulation ascending c 0..63, same values -> bit-identical.
// ---------------------------------------------------------------------------
__global__ __launch_bounds__(256) void k_qkv(
    const float* __restrict__ x,
    const float* __restrict__ Wq, const float* __restrict__ bq,
    const float* __restrict__ Wk, const float* __restrict__ bk,
    const float* __restrict__ Wv, const float* __restrict__ bv,
    float* __restrict__ qs, float* __restrict__ ks, float* __restrict__ vs)
{
    __shared__ float Wt[64][68];                 // 17408 B, transposed weights
    const int tid  = threadIdx.x;
    const int lane = tid & 63;
    const int og   = __builtin_amdgcn_readfirstlane(tid >> 6);  // wave-uniform
    const int tile = blockIdx.x;                 // 0..1023
    const int b    = tile >> 9;
    const int p0   = (tile & 511) << 7;          // 128-px tile
    const int p    = p0 + 2 * lane;
    const int gp   = (b << 16) + p;
    const int wo   = og * 16;

    const float* Ws[3]   = {Wq, Wk, Wv};
    const float* bias[3] = {bq, bk, bv};
    float* outs[3] = {qs + (size_t)gp * 64, ks + (size_t)gp * 64, vs + (size_t)gp * 64};
    const float* xg = x + ((size_t)b * 64) * NPIX + p;

    #pragma unroll
    for (int m = 0; m < 3; ++m) {
        // ---- stage W[m] transposed into LDS (one-time per m-pass) ----
        __syncthreads();   // prior Wt reads complete (no-op for m=0)
        const float* Wm = Ws[m];
        #pragma unroll
        for (int it = 0; it < 4; ++it) {
            const int i  = it * 256 + tid;       // 0..1023
            const int o  = i >> 4;
            const int c4 = i & 15;
            const float4 w = *(const float4*)(Wm + o * 64 + c4 * 4);
            Wt[c4 * 4 + 0][o] = w.x;
            Wt[c4 * 4 + 1][o] = w.y;
            Wt[c4 * 4 + 2][o] = w.z;
            Wt[c4 * 4 + 3][o] = w.w;
        }
        __syncthreads();

        float acc0[16], acc1[16];
        #pragma unroll
        for (int j = 0; j < 16; ++j) { acc0[j] = 0.f; acc1[j] = 0.f; }

        #pragma unroll 4
        for (int c = 0; c < 64; ++c) {           // ascending -> bit-identical
            const float2 xv = *(const float2*)(xg + (size_t)c * NPIX);
            const float4 w0 = *(const float4*)&Wt[c][wo + 0];
            const float4 w1 = *(const float4*)&Wt[c][wo + 4];
            const float4 w2 = *(const float4*)&Wt[c][wo + 8];
            const float4 w3 = *(const float4*)&Wt[c][wo + 12];
            acc0[0]  += w0.x * xv.x; acc1[0]  += w0.x * xv.y;
            acc0[1]  += w0.y * xv.x; acc1[1]  += w0.y * xv.y;
            acc0[2]  += w0.z * xv.x; acc1[2]  += w0.z * xv.y;
            acc0[3]  += w0.w * xv.x; acc1[3]  += w0.w * xv.y;
            acc0[4]  += w1.x * xv.x; acc1[4]  += w1.x * xv.y;
            acc0[5]  += w1.y * xv.x; acc1[5]  += w1.y * xv.y;
            acc0[6]  += w1.z * xv.x; acc1[6]  += w1.z * xv.y;
            acc0[7]  += w1.w * xv.x; acc1[7]  += w1.w * xv.y;
            acc0[8]  += w2.x * xv.x; acc1[8]  += w2.x * xv.y;
            acc0[9]  += w2.y * xv.x; acc1[9]  += w2.y * xv.y;
            acc0[10] += w2.z * xv.x; acc1[10] += w2.z * xv.y;
            acc0[11] += w2.w * xv.x; acc1[11] += w2.w * xv.y;
            acc0[12] += w3.x * xv.x; acc1[12] += w3.x * xv.y;
            acc0[13] += w3.y * xv.x; acc1[13] += w3.y * xv.y;
            acc0[14] += w3.z * xv.x; acc1[14] += w3.z * xv.y;
            acc0[15] += w3.w * xv.x; acc1[15] += w3.w * xv.y;
        }

        const float* bb = bias[m];
        float* o0 = outs[m];
        #pragma unroll
        for (int j4 = 0; j4 < 4; ++j4) {
            float4 v0, v1;
            v0.x = acc0[j4*4+0] + bb[wo + j4*4+0]; v1.x = acc1[j4*4+0] + bb[wo + j4*4+0];
            v0.y = acc0[j4*4+1] + bb[wo + j4*4+1]; v1.y = acc1[j4*4+1] + bb[wo + j4*4+1];
            v0.z = acc0[j4*4+2] + bb[wo + j4*4+2]; v1.z = acc1[j4*4+2] + bb[wo + j4*4+2];
            v0.w = acc0[j4*4+3] + bb[wo + j4*4+3]; v1.w = acc1[j4*4+3] + bb[wo + j4*4+3];
            *(float4*)(o0 + wo + j4*4)      = v0;
            *(float4*)(o0 + 64 + wo + j4*4) = v1;
        }
    }
}

// ---------------------------------------------------------------------------
// K2: conditioning conv (68 -> 17) + channel LayerNorm + lrelu; emits xm.
// REVERTED to round-5 form: pinW via compile-time-offset loads -> s_load
// into the scalar cache (4.6 KB, fits) -- the r6 readlane rewrite doubled
// VALU work for nothing (+17us measured).  Bit-identical arithmetic.
// ---------------------------------------------------------------------------
__global__ __launch_bounds__(256) void k_cond(
    const float* __restrict__ vs, const float* __restrict__ cg,
    const float* __restrict__ pinW, const float* __restrict__ pinb,
    const float* __restrict__ lnw, const float* __restrict__ lnb,
    float* __restrict__ h1, float* __restrict__ xm)
{
    const int gp = blockIdx.x * 256 + threadIdx.x;
    const int b  = gp >> 16;
    const int p  = gp & 65535;
    const int h  = p >> 8;
    const int w  = p & 255;

    float acc[17];
    #pragma unroll
    for (int oc = 0; oc < 17; ++oc) acc[oc] = pinb[oc];

    const float* vp = vs + (size_t)gp * 64;
    #pragma unroll 8
    for (int c4 = 0; c4 < 16; ++c4) {
        const float4 v4 = *(const float4*)(vp + c4 * 4);
        const float vv[4] = {v4.x, v4.y, v4.z, v4.w};
        #pragma unroll
        for (int k = 0; k < 4; ++k) {
            const int c = c4 * 4 + k;
            #pragma unroll
            for (int oc = 0; oc < 17; ++oc)
                acc[oc] += pinW[oc * 68 + c] * vv[k];
        }
    }
    const float c64 = cg[(b * 2 + 0) * NPIX + p];
    const float c65 = cg[(b * 2 + 1) * NPIX + p];
    const float c66 = -1.f + 2.f * (float)(h & 7) / 7.f;
    const float c67 = -1.f + 2.f * (float)(w & 7) / 7.f;
    #pragma unroll
    for (int oc = 0; oc < 17; ++oc)
        acc[oc] += pinW[oc * 68 + 64] * c64 + pinW[oc * 68 + 65] * c65 +
                   pinW[oc * 68 + 66] * c66 + pinW[oc * 68 + 67] * c67;

    float u = 0.f;
    #pragma unroll
    for (int oc = 0; oc < 17; ++oc) u += acc[oc];
    u *= (1.f / 17.f);
    float s = 0.f;
    #pragma unroll
    for (int oc = 0; oc < 17; ++oc) { const float d = acc[oc] - u; s += d * d; }
    s *= (1.f / 17.f);
    const float rstd = rsqrtf(s + 1e-6f);

    float xsum = 0.f;
    #pragma unroll
    for (int oc = 0; oc < 17; ++oc) {
        float hv = lnw[oc] * (acc[oc] - u) * rstd + lnb[oc];
        hv = (hv >= 0.f) ? hv : 0.1f * hv;
        h1[(b * 17 + oc) * NPIX + p] = hv;
        xsum += hv;
    }
    const int win = (h >> 3) * 32 + (w >> 3);
    const int idx = ((h & 7) << 3) | (w & 7);
    xm[(b << 16) + win * 64 + idx] = xsum * (1.f / 17.f);
}

// ---------------------------------------------------------------------------
// K3: 3x3 conv (17 -> 1) + sigmoid -> sa.  (unchanged)
// ---------------------------------------------------------------------------
__global__ __launch_bounds__(256) void k_sa(
    const float* __restrict__ h1, const float* __restrict__ saW,
    const float* __restrict__ sab, float* __restrict__ sa)
{
    __shared__ float S[17 * 3 * 256];
    const int tid = threadIdx.x;
    const int b   = blockIdx.x >> 8;
    const int row = blockIdx.x & 255;

    for (int i = tid; i < 3264; i += 256) {
        const int ch  = i / 192;
        const int rem = i - ch * 192;
        const int dr  = rem >> 6;
        const int c4  = rem & 63;
        const int rr  = row + dr - 1;
        float4 v = {0.f, 0.f, 0.f, 0.f};
        if ((unsigned)rr < 256u)
            v = *(const float4*)(h1 + ((size_t)(b * 17 + ch)) * NPIX + rr * 256 + c4 * 4);
        *(float4*)&S[(ch * 3 + dr) * 256 + c4 * 4] = v;
    }
    __syncthreads();

    const int w = tid;
    float acc = sab[0];
    #pragma unroll 1
    for (int ch = 0; ch < 17; ++ch) {
        #pragma unroll
        for (int dr = 0; dr < 3; ++dr) {
            const float* Sp = &S[(ch * 3 + dr) * 256];
            const float m  = Sp[w];
            const float l  = (w > 0)   ? Sp[w - 1] : 0.f;
            const float r_ = (w < 255) ? Sp[w + 1] : 0.f;
            const float* Wp = saW + (ch * 3 + dr) * 3;
            acc += Wp[0] * l + Wp[1] * m + Wp[2] * r_;
        }
    }
    sa[b * NPIX + row * 256 + w] = 1.f / (1.f + __expf(-acc));
}

// ---------------------------------------------------------------------------
// K4: window scoring MLP + stable-argsort partition.  (round-5 version)
// ---------------------------------------------------------------------------
__global__ __launch_bounds__(1024) void k_score_select(
    const float* __restrict__ xm,
    const float* __restrict__ m1W, const float* __restrict__ m1b,
    const float* __restrict__ m2W, const float* __restrict__ m2b,
    int* __restrict__ flag, int* __restrict__ kept)
{
    __shared__ float sc[NW];
    const int b = blockIdx.x;
    const int t = threadIdx.x;

    float z[8];
    #pragma unroll
    for (int jj = 0; jj < 8; ++jj) z[jj] = m1b[jj];

    const float* xw = xm + (b << 16) + t * 64;
    #pragma unroll 4
    for (int t4 = 0; t4 < 16; ++t4) {
        const float4 v4 = *(const float4*)(xw + t4 * 4);
        const float vv[4] = {v4.x, v4.y, v4.z, v4.w};
        #pragma unroll
        for (int k = 0; k < 4; ++k) {
            const int tt = t4 * 4 + k;           // ascending 0..63
            #pragma unroll
            for (int jj = 0; jj < 8; ++jj)
                z[jj] += m1W[jj * 64 + tt] * vv[k];
        }
    }
    #pragma unroll
    for (int jj = 0; jj < 8; ++jj) z[jj] = (z[jj] >= 0.f) ? z[jj] : 0.1f * z[jj];

    float l0 = m2b[0], l1 = m2b[1];
    #pragma unroll
    for (int jj = 0; jj < 8; ++jj) { l0 += m2W[jj] * z[jj]; l1 += m2W[8 + jj] * z[jj]; }
    const float mx = fmaxf(l0, l1);
    const float e0 = expf(l0 - mx), e1 = expf(l1 - mx);
    sc[t] = e0 / (e0 + e1);
    __syncthreads();

    const float s = sc[t];
    int cnt = 0;
    for (int jq = 0; jq < NW; jq += 4) {
        const float4 s4 = *(const float4*)&sc[jq];
        cnt += (s4.x > s) || (s4.x == s && (jq + 0) < t);
        cnt += (s4.y > s) || (s4.y == s && (jq + 1) < t);
        cnt += (s4.z > s) || (s4.z == s && (jq + 2) < t);
        cnt += (s4.w > s) || (s4.w == s && (jq + 3) < t);
    }
    flag[b * NW + t] = (cnt < KEEP) ? 1 : 0;
    if (cnt < KEEP) kept[b * KEEP + cnt] = t;
}

// ---------------------------------------------------------------------------
// K5: windowed attention, HYBRID v2 (pressure-controlled).
// r6 proved the hybrid's NUMERICS (passed, bit-identical) but spilled
// (VGPR target 64 vs ~75 live -> 1.25GB scratch).  v2 squeezes the live set
// under 64: cw[12] lives in LDS (CW[col][tid], lanes consecutive ->
// conflict-free), V-broadcasts are inlined one-at-a-time (no vd[] array),
// plain __launch_bounds__(256) (r3's allocator gave 72 VGPR / no spill on
// the same shape of live set).  K via LDS uniform b128 (4/key), V via
// lane-distributed global + readlane: LDS/CU ~= 39us, VALU/SIMD ~= 40us.
// Key order and per-key FP sequence identical to r3-r6 -> bit-identical.
// SPILL TRIPWIRE: WRITE_SIZE must stay ~16.4MB.
// ---------------------------------------------------------------------------
__global__ __launch_bounds__(256) void k_attn(
    const float* __restrict__ qs, const float* __restrict__ ks,
    const float* __restrict__ vs, const int* __restrict__ kept,
    const float* __restrict__ relh, const float* __restrict__ relw,
    float* __restrict__ amix)
{
    __shared__ float SK[144 * 64];   // 36864 B: K for all 144 patch px
    __shared__ float CW[12 * 256];   // 12288 B: cw[col][tid]
    const int b    = blockIdx.y;
    const int win  = kept[b * KEEP + blockIdx.x];
    const int wy = win >> 5, wx = win & 31;
    const int tid  = threadIdx.x;
    const int head = __builtin_amdgcn_readfirstlane(tid >> 6);
    const int lane = tid & 63;
    const int choff = head * 16;
    const size_t bbase = (size_t)b * NPIX;
    const int px0 = (wy * 8) * 256 + wx * 8;
    const int qrow = lane >> 3, qcol = lane & 7;
    const int sub = lane >> 4, d_ = lane & 15;
    const int wy8 = wy * 8 - 2, wx8 = wx * 8 - 2;

    // ---- stage K for all 144 keys (2304 float4, 9/thread, coalesced) ----
    #pragma unroll
    for (int it = 0; it < 9; ++it) {
        const int i   = it * 256 + tid;
        const int pxl = i >> 4;                  // 0..143
        const int c4  = i & 15;
        const int rl  = pxl / 12;
        const int col = pxl - rl * 12;
        const int ry  = wy8 + rl;
        const int cx  = wx8 + col;
        float4 kv = {0.f, 0.f, 0.f, 0.f};
        if ((unsigned)ry < 256u && (unsigned)cx < 256u)
            kv = *(const float4*)(ks + (bbase + (size_t)(ry * 256 + cx)) * 64 + c4 * 4);
        *(float4*)&SK[pxl * 64 + c4 * 4] = kv;
    }

    // ---- q direct from global (same values, x0.25) ----
    float q[16];
    {
        const float* qp = qs + (bbase + px0 + qrow * 256 + qcol) * 64 + choff;
        #pragma unroll
        for (int j4 = 0; j4 < 4; ++j4) {
            const float4 v = *(const float4*)(qp + j4 * 4);
            q[j4 * 4 + 0] = v.x * 0.25f; q[j4 * 4 + 1] = v.y * 0.25f;
            q[j4 * 4 + 2] = v.z * 0.25f; q[j4 * 4 + 3] = v.w * 0.25f;
        }
    }

    // ---- column rel-pos coefficients -> LDS (identical arithmetic) ----
    #pragma unroll
    for (int k = 0; k < 12; ++k) {
        const float* rw = relw + (k - qcol + 11) * 16;
        float sw = 0.f;
        #pragma unroll
        for (int j4 = 0; j4 < 4; ++j4) {
            const float4 w4 = *(const float4*)(rw + j4 * 4);
            sw += q[j4*4+0]*w4.x + q[j4*4+1]*w4.y + q[j4*4+2]*w4.z + q[j4*4+3]*w4.w;
        }
        CW[k * 256 + tid] = sw;
    }

    const int laneoff = choff + d_;

    float sum = 0.f;
    float vo[16];
    #pragma unroll
    for (int d = 0; d < 16; ++d) vo[d] = 0.f;

    __syncthreads();   // SK + CW staged

    #pragma unroll 1
    for (int r = 0; r < 12; ++r) {               // patch row (12 keys each)
        const int ry = wy8 + r;
        const bool rowok = (unsigned)ry < 256u;

        // V for this row's 3 groups, lane-distributed (issued early so HBM/L2
        // latency hides under srow + the first QK blocks)
        float vg0 = 0.f, vg1 = 0.f, vg2 = 0.f;
        if (rowok) {
            const size_t rowa = bbase + (size_t)(ry * 256);
            const int cx0 = wx8 + sub, cx1 = cx0 + 4, cx2 = cx0 + 8;
            if ((unsigned)cx0 < 256u) vg0 = vs[(rowa + cx0) * 64 + laneoff];
            if ((unsigned)cx1 < 256u) vg1 = vs[(rowa + cx1) * 64 + laneoff];
            if ((unsigned)cx2 < 256u) vg2 = vs[(rowa + cx2) * 64 + laneoff];
        }

        // row rel-pos coefficient (same instruction sequence)
        const float* rh = relh + (r - qrow + 11) * 16;
        float srow = 0.f;
        #pragma unroll
        for (int j4 = 0; j4 < 4; ++j4) {
            const float4 h4 = *(const float4*)(rh + j4 * 4);
            srow += q[j4*4+0]*h4.x + q[j4*4+1]*h4.y + q[j4*4+2]*h4.z + q[j4*4+3]*h4.w;
        }

        #pragma unroll
        for (int gi = 0; gi < 3; ++gi) {         // 4-key groups within the row
            const float vg = (gi == 0) ? vg0 : (gi == 1) ? vg1 : vg2;
            #pragma unroll
            for (int kk = 0; kk < 4; ++kk) {     // key col = 4*gi + kk
                const int col = 4 * gi + kk;
                const float* kb = &SK[(r * 12 + col) * 64 + choff]; // uniform
                const float4 k0 = *(const float4*)(kb + 0);
                const float4 k1 = *(const float4*)(kb + 4);
                const float4 k2 = *(const float4*)(kb + 8);
                const float4 k3 = *(const float4*)(kb + 12);
                float s = srow + CW[col * 256 + tid];
                s += k0.x*q[0];  s += k0.y*q[1];  s += k0.z*q[2];  s += k0.w*q[3];
                s += k1.x*q[4];  s += k1.y*q[5];  s += k1.z*q[6];  s += k1.w*q[7];
                s += k2.x*q[8];  s += k2.y*q[9];  s += k2.z*q[10]; s += k2.w*q[11];
                s += k3.x*q[12]; s += k3.y*q[13]; s += k3.z*q[14]; s += k3.w*q[15];
                const float e = __expf(s);
                sum += e;
                // V broadcast inlined scalar-at-a-time (1 live temp)
                vo[0]  += e * bcast(vg, kk * 16 + 0);
                vo[1]  += e * bcast(vg, kk * 16 + 1);
                vo[2]  += e * bcast(vg, kk * 16 + 2);
                vo[3]  += e * bcast(vg, kk * 16 + 3);
                vo[4]  += e * bcast(vg, kk * 16 + 4);
                vo[5]  += e * bcast(vg, kk * 16 + 5);
                vo[6]  += e * bcast(vg, kk * 16 + 6);
                vo[7]  += e * bcast(vg, kk * 16 + 7);
                vo[8]  += e * bcast(vg, kk * 16 + 8);
                vo[9]  += e * bcast(vg, kk * 16 + 9);
                vo[10] += e * bcast(vg, kk * 16 + 10);
                vo[11] += e * bcast(vg, kk * 16 + 11);
                vo[12] += e * bcast(vg, kk * 16 + 12);
                vo[13] += e * bcast(vg, kk * 16 + 13);
                vo[14] += e * bcast(vg, kk * 16 + 14);
                vo[15] += e * bcast(vg, kk * 16 + 15);
            }
        }
    }

    // ---- epilogue: normalize, direct store of this head's 16-ch slice ----
    const float inv = 1.f / sum;
    float* op = amix + (bbase + px0 + qrow * 256 + qcol) * 64 + choff;
    #pragma unroll
    for (int j4 = 0; j4 < 4; ++j4) {
        float4 v;
        v.x = vo[j4*4+0] * inv; v.y = vo[j4*4+1] * inv;
        v.z = vo[j4*4+2] * inv; v.w = vo[j4*4+3] * inv;
        *(float4*)(op + j4 * 4) = v;
    }
}

// ---------------------------------------------------------------------------
// K6: final 1x1 conv (64 -> 64) with fused easy path.  r4 Wt-LDS structure
// with 2 px/lane (halves waves -> halves the uniform-b128 LDS cost, same
// lever as K1).  Per-output FP order (c ascending, +bias) identical.
// ---------------------------------------------------------------------------
__global__ __launch_bounds__(256) void k_out_f(
    const float* __restrict__ amix, const float* __restrict__ vs,
    const float* __restrict__ sa, const int* __restrict__ flag,
    const float* __restrict__ W, const float* __restrict__ bias,
    float* __restrict__ out)
{
    __shared__ float xs[64][130];                // 33280 B
    __shared__ float Wt[64][68];                 // 17408 B
    __shared__ float smult[128];
    __shared__ int   sflag[128];
    const int tid  = threadIdx.x;
    const int lane = tid & 63;
    const int og   = __builtin_amdgcn_readfirstlane(tid >> 6);
    const int tile = blockIdx.x;                 // 0..1023
    const int b    = tile >> 9;
    const int p0   = (tile & 511) << 7;          // 128-px tile
    const int wo   = og * 16;

    // ---- stage Wout transposed (one-time) ----
    #pragma unroll
    for (int it = 0; it < 4; ++it) {
        const int i  = it * 256 + tid;
        const int o  = i >> 4;
        const int c4 = i & 15;
        const float4 w = *(const float4*)(W + o * 64 + c4 * 4);
        Wt[c4 * 4 + 0][o] = w.x;
        Wt[c4 * 4 + 1][o] = w.y;
        Wt[c4 * 4 + 2][o] = w.z;
        Wt[c4 * 4 + 3][o] = w.w;
    }

    if (tid < 128) {
        const int p   = p0 + tid;
        const int h   = p >> 8, w_ = p & 255;
        const int win = (h >> 3) * 32 + (w_ >> 3);
        const int fl  = flag[b * NW + win];
        sflag[tid] = fl;
        smult[tid] = fl ? 1.f : sa[(b << 16) + p];
    }
    __syncthreads();

    // stage 128 px x 64 ch with mult applied; NHWC float4 reads (coalesced),
    // transposed scalar LDS writes
    #pragma unroll
    for (int it = 0; it < 8; ++it) {
        const int i   = it * 256 + tid;
        const int pxl = i >> 4;                  // 0..127
        const int c4  = i & 15;
        const int gpl = (b << 16) + p0 + pxl;
        const float* src = (sflag[pxl] ? amix : vs) + (size_t)gpl * 64;
        const float m = smult[pxl];
        const float4 v = *(const float4*)(src + c4 * 4);
        xs[c4 * 4 + 0][pxl] = v.x * m;
        xs[c4 * 4 + 1][pxl] = v.y * m;
        xs[c4 * 4 + 2][pxl] = v.z * m;
        xs[c4 * 4 + 3][pxl] = v.w * m;
    }
    __syncthreads();

    float acc0[16], acc1[16];
    #pragma unroll
    for (int j = 0; j < 16; ++j) { acc0[j] = 0.f; acc1[j] = 0.f; }

    #pragma unroll 4
    for (int c = 0; c < 64; ++c) {               // ascending -> bit-identical
        const float2 xv = *(const float2*)&xs[c][2 * lane];
        const float4 w0 = *(const float4*)&Wt[c][wo + 0];
        const float4 w1 = *(const float4*)&Wt[c][wo + 4];
        const float4 w2 = *(const float4*)&Wt[c][wo + 8];
        const float4 w3 = *(const float4*)&Wt[c][wo + 12];
        acc0[0]  += w0.x * xv.x; acc1[0]  += w0.x * xv.y;
        acc0[1]  += w0.y * xv.x; acc1[1]  += w0.y * xv.y;
        acc0[2]  += w0.z * xv.x; acc1[2]  += w0.z * xv.y;
        acc0[3]  += w0.w * xv.x; acc1[3]  += w0.w * xv.y;
        acc0[4]  += w1.x * xv.x; acc1[4]  += w1.x * xv.y;
        acc0[5]  += w1.y * xv.x; acc1[5]  += w1.y * xv.y;
        acc0[6]  += w1.z * xv.x; acc1[6]  += w1.z * xv.y;
        acc0[7]  += w1.w * xv.x; acc1[7]  += w1.w * xv.y;
        acc0[8]  += w2.x * xv.x; acc1[8]  += w2.x * xv.y;
        acc0[9]  += w2.y * xv.x; acc1[9]  += w2.y * xv.y;
        acc0[10] += w2.z * xv.x; acc1[10] += w2.z * xv.y;
        acc0[11] += w2.w * xv.x; acc1[11] += w2.w * xv.y;
        acc0[12] += w3.x * xv.x; acc1[12] += w3.x * xv.y;
        acc0[13] += w3.y * xv.x; acc1[13] += w3.y * xv.y;
        acc0[14] += w3.z * xv.x; acc1[14] += w3.z * xv.y;
        acc0[15] += w3.w * xv.x; acc1[15] += w3.w * xv.y;
    }

    const int p    = p0 + 2 * lane;
    const int base = (b << 6) * NPIX + p;
    #pragma unroll
    for (int j = 0; j < 16; ++j) {
        const float bj = bias[wo + j];
        out[base +     (wo + j) * NPIX] = acc0[j] + bj;
        out[base + 1 + (wo + j) * NPIX] = acc1[j] + bj;
    }
}

// ---------------------------------------------------------------------------
extern "C" void kernel_launch(void* const* d_in, const int* in_sizes, int n_in,
                              void* d_out, int out_size, void* d_ws, size_t ws_size,
                              hipStream_t stream)
{
    const float* x    = (const float*)d_in[0];
    const float* cg   = (const float*)d_in[1];
    const float* Wq   = (const float*)d_in[2];
    const float* bq   = (const float*)d_in[3];
    const float* Wk   = (const float*)d_in[4];
    const float* bk   = (const float*)d_in[5];
    const float* Wv   = (const float*)d_in[6];
    const float* bv   = (const float*)d_in[7];
    const float* Wout = (const float*)d_in[8];
    const float* bout = (const float*)d_in[9];
    const float* relh = (const float*)d_in[10];
    const float* relw = (const float*)d_in[11];
    const float* pinW = (const float*)d_in[12];
    const float* pinb = (const float*)d_in[13];
    const float* lnw  = (const float*)d_in[14];
    const float* lnb  = (const float*)d_in[15];
    const float* saW  = (const float*)d_in[16];
    const float* sab  = (const float*)d_in[17];
    const float* m1W  = (const float*)d_in[18];
    const float* m1b  = (const float*)d_in[19];
    const float* m2W  = (const float*)d_in[20];
    const float* m2b  = (const float*)d_in[21];
    float* out = (float*)d_out;

    // workspace layout (floats); qs doubles as the assembled "amix" tensor
    float* ws    = (float*)d_ws;
    float* qs    = ws;                       // 64*NPIXT (NHWC, aliased amix)
    float* ks    = qs + 8388608;             // NHWC
    float* vs    = ks + 8388608;             // NHWC
    float* h1    = vs + 8388608;             // 17 * NPIXT (NCHW)
    float* xm    = h1 + 17 * NPIXT;          // NPIXT (window-major)
    float* sa    = xm + NPIXT;               // NPIXT
    int*   flag  = (int*)(sa + NPIXT);       // 2048
    int*   kept  = flag + 2048;              // 1024

    k_qkv         <<<1024, 256, 0, stream>>>(x, Wq, bq, Wk, bk, Wv, bv, qs, ks, vs);
    k_cond        <<<NPIXT / 256, 256, 0, stream>>>(vs, cg, pinW, pinb, lnw, lnb, h1, xm);
    k_sa          <<<512, 256, 0, stream>>>(h1, saW, sab, sa);
    k_score_select<<<2, 1024, 0, stream>>>(xm, m1W, m1b, m2W, m2b, flag, kept);
    k_attn        <<<dim3(KEEP, 2), 256, 0, stream>>>(qs, ks, vs, kept, relh, relw, qs);
    k_out_f       <<<1024, 256, 0, stream>>>(qs, vs, sa, flag, Wout, bout, out);
}